// Round 1
// baseline (656.681 us; speedup 1.0000x reference)
//
#include <hip/hip_runtime.h>
#include <math.h>

// BCAM: x1,x2 [8,192,128,128] f32. heads=8, c=24, temperature=0.01.
// R4: all-bf16 MFMA pipeline.
//   conv1/2 (f32 in -> bf16 out), norms (bf16 in),
//   scores+softmax fused (bf16 MFMA, full K, P bf16 w/ gate pre-scale),
//   pv (all-bf16 staging, fusion bf16 -> d_out scratch),
//   conv5/6/7 (bf16 in; conv7 -> f32 d_out + x1 + x2).
// R5: scores_softmax k-loop register-prefetch pipeline (T14 issue-early/
//   write-late). scores runs 1 wave/SIMD (grid 256 blocks) -> no TLP; the
//   old loop serialized {load -> barrier -> MFMA} paying full global-load
//   latency per step. Now next step's loads are issued before current
//   step's MFMA; LDS write happens after the post-MFMA barrier. Occupancy
//   is grid-limited here, so the +32 VGPR prefetch regs are free.
// Numerics: bf16 rounding errors enter logits as ~100*3e-3/sqrt(3072) ~ 0.005
// (RMS, random-sign) — far below the 0.152 threshold. R3 evidence: bf16 P/V
// left absmax unchanged at 0.03125.
// pos_bias dropped (per-head scalar, softmax shift-invariant).
// V = UNNORMALIZED tokens (v1=k1 binds before l2norm).

#define N_PIX 16384
#define W_DIM 128
#define C_DIM 192
#define C_PH  24
#define ELEMS 25165824  // 8*192*128*128
#define TINV  100.0f

typedef __bf16 bf16x8 __attribute__((ext_vector_type(8)));
typedef float  f32x4  __attribute__((ext_vector_type(4)));

__device__ __forceinline__ unsigned short f2bf(float f) {
    union { float f; unsigned u; } x; x.f = f;
    unsigned r = x.u + 0x7FFF + ((x.u >> 16) & 1);
    return (unsigned short)(r >> 16);
}
__device__ __forceinline__ float bf2f(unsigned short h) {
    union { unsigned u; float f; } x; x.u = ((unsigned)h) << 16; return x.f;
}
__device__ __forceinline__ unsigned pack2(unsigned short a, unsigned short b) {
    return (unsigned)a | ((unsigned)b << 16);
}

// ---------------------------------------------------------------------------
// conv1x1, f32 input -> bf16 output (conv1/conv2).
// grid (64 p-tiles, 3 m-tiles, 8 b), block 256. Tile 64m x 256p.
// ---------------------------------------------------------------------------
__global__ __launch_bounds__(256)
void conv_f32in(const float* __restrict__ X, const float* __restrict__ Wt,
                const float* __restrict__ bias, unsigned short* __restrict__ Y)
{
    __shared__ unsigned short Ah[64][40];
    __shared__ unsigned short Bh[256][40];

    const int tid = threadIdx.x;
    const int p0 = blockIdx.x << 8;
    const int m0 = blockIdx.y << 6;
    const int b  = blockIdx.z;
    const float* Xb = X + (size_t)b * C_DIM * N_PIX;

    const int wave = tid >> 6, lane = tid & 63;
    const int quad = lane >> 4, l16 = lane & 15;
    const int mw = (wave & 1) << 5;
    const int nw = (wave >> 1) << 7;
    const int koff = quad << 3;

    f32x4 acc[2][8];
    #pragma unroll
    for (int i = 0; i < 2; ++i)
        #pragma unroll
        for (int j = 0; j < 8; ++j) acc[i][j] = (f32x4){0.f, 0.f, 0.f, 0.f};

    for (int k0 = 0; k0 < C_DIM; k0 += 32) {
        // A (weights) 64m x 32k
        #pragma unroll
        for (int i = 0; i < 2; ++i) {
            const int a = (tid << 1) + i;
            const int m = a >> 3, kq = a & 7;
            const float4 v = *(const float4*)(Wt + (size_t)(m0 + m) * C_DIM + k0 + (kq << 2));
            uint2 pk; pk.x = pack2(f2bf(v.x), f2bf(v.y)); pk.y = pack2(f2bf(v.z), f2bf(v.w));
            *(uint2*)(&Ah[m][kq << 2]) = pk;
        }
        // B (pixels) 32k x 256p, 4x4 transpose. kq in low bits -> spread banks.
        #pragma unroll
        for (int r = 0; r < 2; ++r) {
            const int u = tid + (r << 8);
            const int kq = u & 7, p4 = (u >> 3) << 2;
            float4 f[4];
            #pragma unroll
            for (int i = 0; i < 4; ++i)
                f[i] = *(const float4*)(Xb + (size_t)(k0 + (kq << 2) + i) * N_PIX + p0 + p4);
            #pragma unroll
            for (int j = 0; j < 4; ++j) {
                uint2 pk;
                pk.x = pack2(f2bf((&f[0].x)[j]), f2bf((&f[1].x)[j]));
                pk.y = pack2(f2bf((&f[2].x)[j]), f2bf((&f[3].x)[j]));
                *(uint2*)(&Bh[p4 + j][kq << 2]) = pk;
            }
        }
        __syncthreads();

        bf16x8 af[2];
        #pragma unroll
        for (int mf = 0; mf < 2; ++mf)
            af[mf] = *(const bf16x8*)(&Ah[mw + (mf << 4) + l16][koff]);
        #pragma unroll
        for (int nf = 0; nf < 8; ++nf) {
            const bf16x8 bfr = *(const bf16x8*)(&Bh[nw + (nf << 4) + l16][koff]);
            #pragma unroll
            for (int mf = 0; mf < 2; ++mf)
                acc[mf][nf] = __builtin_amdgcn_mfma_f32_16x16x32_bf16(af[mf], bfr, acc[mf][nf], 0, 0, 0);
        }
        __syncthreads();
    }

    const size_t outb = (size_t)b * C_DIM * N_PIX;
    #pragma unroll
    for (int mf = 0; mf < 2; ++mf) {
        #pragma unroll
        for (int r = 0; r < 4; ++r) {
            const int m = m0 + mw + (mf << 4) + (quad << 2) + r;
            const float bm = bias[m];
            const size_t row = outb + (size_t)m * N_PIX;
            #pragma unroll
            for (int nf = 0; nf < 8; ++nf) {
                const int p = p0 + nw + (nf << 4) + l16;
                Y[row + p] = f2bf(acc[mf][nf][r] + bm);
            }
        }
    }
}

// ---------------------------------------------------------------------------
// conv1x1, bf16 input (conv5/6/7). MODE 0: bf16 out; 1: GELU, bf16 out;
// 2: + R1 + R2 (f32), f32 out.
// ---------------------------------------------------------------------------
template<int MODE>
__global__ __launch_bounds__(256)
void conv_b16in(const unsigned short* __restrict__ X, const float* __restrict__ Wt,
                const float* __restrict__ bias, void* __restrict__ Yv,
                const float* __restrict__ R1, const float* __restrict__ R2)
{
    __shared__ unsigned short Ah[64][40];
    __shared__ unsigned short Bh[256][40];

    const int tid = threadIdx.x;
    const int p0 = blockIdx.x << 8;
    const int m0 = blockIdx.y << 6;
    const int b  = blockIdx.z;
    const unsigned short* Xb = X + (size_t)b * C_DIM * N_PIX;

    const int wave = tid >> 6, lane = tid & 63;
    const int quad = lane >> 4, l16 = lane & 15;
    const int mw = (wave & 1) << 5;
    const int nw = (wave >> 1) << 7;
    const int koff = quad << 3;

    f32x4 acc[2][8];
    #pragma unroll
    for (int i = 0; i < 2; ++i)
        #pragma unroll
        for (int j = 0; j < 8; ++j) acc[i][j] = (f32x4){0.f, 0.f, 0.f, 0.f};

    for (int k0 = 0; k0 < C_DIM; k0 += 32) {
        #pragma unroll
        for (int i = 0; i < 2; ++i) {
            const int a = (tid << 1) + i;
            const int m = a >> 3, kq = a & 7;
            const float4 v = *(const float4*)(Wt + (size_t)(m0 + m) * C_DIM + k0 + (kq << 2));
            uint2 pk; pk.x = pack2(f2bf(v.x), f2bf(v.y)); pk.y = pack2(f2bf(v.z), f2bf(v.w));
            *(uint2*)(&Ah[m][kq << 2]) = pk;
        }
        // B: 32k x 256p. Thread: 4 k-rows (kq) x 8 p. Pure ushort transpose.
        {
            const int kq = tid & 7, pg = (tid >> 3) << 3;
            uint4 f[4];
            #pragma unroll
            for (int i = 0; i < 4; ++i)
                f[i] = *(const uint4*)(Xb + (size_t)(k0 + (kq << 2) + i) * N_PIX + p0 + pg);
            #pragma unroll
            for (int j = 0; j < 8; ++j) {
                const unsigned short e0 = ((const unsigned short*)&f[0])[j];
                const unsigned short e1 = ((const unsigned short*)&f[1])[j];
                const unsigned short e2 = ((const unsigned short*)&f[2])[j];
                const unsigned short e3 = ((const unsigned short*)&f[3])[j];
                uint2 pk; pk.x = pack2(e0, e1); pk.y = pack2(e2, e3);
                *(uint2*)(&Bh[pg + j][kq << 2]) = pk;
            }
        }
        __syncthreads();

        bf16x8 af[2];
        #pragma unroll
        for (int mf = 0; mf < 2; ++mf)
            af[mf] = *(const bf16x8*)(&Ah[mw + (mf << 4) + l16][koff]);
        #pragma unroll
        for (int nf = 0; nf < 8; ++nf) {
            const bf16x8 bfr = *(const bf16x8*)(&Bh[nw + (nf << 4) + l16][koff]);
            #pragma unroll
            for (int mf = 0; mf < 2; ++mf)
                acc[mf][nf] = __builtin_amdgcn_mfma_f32_16x16x32_bf16(af[mf], bfr, acc[mf][nf], 0, 0, 0);
        }
        __syncthreads();
    }

    const size_t outb = (size_t)b * C_DIM * N_PIX;
    #pragma unroll
    for (int mf = 0; mf < 2; ++mf) {
        #pragma unroll
        for (int r = 0; r < 4; ++r) {
            const int m = m0 + mw + (mf << 4) + (quad << 2) + r;
            const float bm = bias[m];
            const size_t row = outb + (size_t)m * N_PIX;
            #pragma unroll
            for (int nf = 0; nf < 8; ++nf) {
                const int p = p0 + nw + (nf << 4) + l16;
                float v = acc[mf][nf][r] + bm;
                if (MODE == 1) v = 0.5f * v * (1.0f + erff(v * 0.70710678118654752f));
                if (MODE == 2) {
                    v += R1[row + p] + R2[row + p];
                    ((float*)Yv)[row + p] = v;
                } else {
                    ((unsigned short*)Yv)[row + p] = f2bf(v);
                }
            }
        }
    }
}

// ---------------------------------------------------------------------------
// Token sum-of-squares from bf16 out1/out2. norms[src][b][n][dir*128+t].
// ---------------------------------------------------------------------------
__global__ __launch_bounds__(256)
void norms_kernel(const unsigned short* __restrict__ o1,
                  const unsigned short* __restrict__ o2,
                  float* __restrict__ norms)
{
    __shared__ float hsum[128];
    __shared__ float wsum[128];
    const int tid = threadIdx.x;
    const int b = blockIdx.x, n = blockIdx.y;
    const int src = blockIdx.z >> 2, qt = blockIdx.z & 3;
    const unsigned short* basep = (src == 0 ? o1 : o2)
        + (size_t)b * C_DIM * N_PIX + (size_t)n * C_PH * N_PIX + (size_t)(qt * 6) * N_PIX;

    if (tid < 128) hsum[tid] = 0.0f;
    __syncthreads();

    const int tx = tid & 127, ty = tid >> 7;
    float accw = 0.0f;
    for (int hh = 0; hh < 64; ++hh) {
        const int h = (hh << 1) + ty;
        float rowacc = 0.0f;
        #pragma unroll
        for (int ch = 0; ch < 6; ++ch) {
            const float v = bf2f(basep[(size_t)ch * N_PIX + h * W_DIM + tx]);
            rowacc += v * v;
        }
        accw += rowacc;
        #pragma unroll
        for (int off = 32; off > 0; off >>= 1) rowacc += __shfl_down(rowacc, off);
        if ((tid & 63) == 0) atomicAdd(&hsum[h], rowacc);
    }
    if (ty == 0) wsum[tx] = accw;
    __syncthreads();
    if (ty == 1) wsum[tx] += accw;
    __syncthreads();

    float* np_ = norms + ((size_t)(src * 8 + b) * 8 + n) * 256;
    if (tid < 128) atomicAdd(&np_[tid], hsum[tid]);
    else           atomicAdd(&np_[tid], wsum[tid - 128]);
}

// ---------------------------------------------------------------------------
// Fused scores+softmax: S = Qbf.Kbf^T (full K=3072), scale 100*rq*rk, row
// softmax, pre-scale by gate weight, write P bf16.
// grid (2 i-tiles, 64 bn, 2 dir), block 256 (4 waves x 16 i-rows).
// R5: register-prefetch pipelined k-loop. Occupancy is grid-limited
// (1 wave/SIMD) so prefetch VGPRs are free; loads for step ks+1 are issued
// before step ks's MFMA, ds_write deferred to after the post-MFMA barrier.
// ---------------------------------------------------------------------------
__global__ __launch_bounds__(256)
void scores_softmax(const unsigned short* __restrict__ o1,
                    const unsigned short* __restrict__ o2,
                    const float* __restrict__ norms, const float* __restrict__ gate,
                    unsigned short* __restrict__ P)
{
    __shared__ unsigned short Qh[64][40];
    __shared__ unsigned short Kh[128][40];
    __shared__ float rqv[64], rkv[128];

    const int tid = threadIdx.x;
    const int i0  = blockIdx.x << 6;
    const int bn  = blockIdx.y;
    const int dir = blockIdx.z;
    const int b = bn >> 3, n = bn & 7;

    const size_t base = (size_t)b * C_DIM * N_PIX + (size_t)n * C_PH * N_PIX;
    const unsigned short* Qb = (dir == 0 ? o2 : o1) + base;
    const unsigned short* Kb = (dir == 0 ? o1 : o2) + base;

    const int qsrc = (dir == 0) ? 1 : 0;
    const float* qn_g = norms + ((size_t)(qsrc * 8 + b) * 8 + n) * 256 + dir * 128;
    const float* kn_g = norms + ((size_t)((1 - qsrc) * 8 + b) * 8 + n) * 256 + dir * 128;

    if (tid < 64)        rqv[tid]      = TINV * rsqrtf(fmaxf(qn_g[i0 + tid], 1e-24f));
    else if (tid < 192)  rkv[tid - 64] = rsqrtf(fmaxf(kn_g[tid - 64], 1e-24f));

    const int wave = tid >> 6, lane = tid & 63;
    const int quad = lane >> 4, l16 = lane & 15;
    const int koff = quad << 3;

    f32x4 acc[8];
    #pragma unroll
    for (int j = 0; j < 8; ++j) acc[j] = (f32x4){0.f, 0.f, 0.f, 0.f};

    // --- staging helpers ---------------------------------------------------
    auto load_step = [&](int ks, uint4* pf) {
        const int ch = ks >> 2;
        const int x0 = (ks & 3) << 5;
        const size_t cb = (size_t)ch * N_PIX;
        if (dir == 0) {
            // tokens = h-rows, k along w: natural k-contiguous rows.
            const int row = tid >> 2, q4 = tid & 3;
            pf[0] = *(const uint4*)(Qb + cb + (size_t)(i0 + row) * W_DIM + x0 + (q4 << 3));
            pf[1] = *(const uint4*)(Kb + cb + (size_t)row * W_DIM + x0 + (q4 << 3));
            pf[2] = *(const uint4*)(Kb + cb + (size_t)(64 + row) * W_DIM + x0 + (q4 << 3));
        } else {
            // tokens = w-cols, k along h: loads for 4x8 ushort transpose.
            if (tid < 64) {
                const int wg = tid >> 3, kq = tid & 7;
                #pragma unroll
                for (int i = 0; i < 4; ++i)
                    pf[i] = *(const uint4*)(Qb + cb + (size_t)(x0 + (kq << 2) + i) * W_DIM + i0 + (wg << 3));
            } else if (tid < 192) {
                const int u = tid - 64;
                const int wg = u >> 3, kq = u & 7;
                #pragma unroll
                for (int i = 0; i < 4; ++i)
                    pf[i] = *(const uint4*)(Kb + cb + (size_t)(x0 + (kq << 2) + i) * W_DIM + (wg << 3));
            }
        }
    };
    auto store_step = [&](const uint4* pf) {
        if (dir == 0) {
            const int row = tid >> 2, q4 = tid & 3;
            *(uint4*)(&Qh[row][q4 << 3])      = pf[0];
            *(uint4*)(&Kh[row][q4 << 3])      = pf[1];
            *(uint4*)(&Kh[64 + row][q4 << 3]) = pf[2];
        } else {
            if (tid < 64) {
                const int wg = tid >> 3, kq = tid & 7;
                #pragma unroll
                for (int j = 0; j < 8; ++j) {
                    uint2 pk;
                    pk.x = pack2(((const unsigned short*)&pf[0])[j], ((const unsigned short*)&pf[1])[j]);
                    pk.y = pack2(((const unsigned short*)&pf[2])[j], ((const unsigned short*)&pf[3])[j]);
                    *(uint2*)(&Qh[(wg << 3) + j][kq << 2]) = pk;
                }
            } else if (tid < 192) {
                const int u = tid - 64;
                const int wg = u >> 3, kq = u & 7;
                #pragma unroll
                for (int j = 0; j < 8; ++j) {
                    uint2 pk;
                    pk.x = pack2(((const unsigned short*)&pf[0])[j], ((const unsigned short*)&pf[1])[j]);
                    pk.y = pack2(((const unsigned short*)&pf[2])[j], ((const unsigned short*)&pf[3])[j]);
                    *(uint2*)(&Kh[(wg << 3) + j][kq << 2]) = pk;
                }
            }
        }
    };
    auto compute_step = [&]() {
        const bf16x8 a = *(const bf16x8*)(&Qh[(wave << 4) + l16][koff]);
        #pragma unroll
        for (int nf = 0; nf < 8; ++nf) {
            const bf16x8 bfr = *(const bf16x8*)(&Kh[(nf << 4) + l16][koff]);
            acc[nf] = __builtin_amdgcn_mfma_f32_16x16x32_bf16(a, bfr, acc[nf], 0, 0, 0);
        }
    };

    // --- pipelined k-loop: 2 steps/iter with named prefetch regs (rule #20)
    uint4 pfA[4], pfB[4];
    load_step(0, pfA);
    for (int ks = 0; ks < 96; ks += 2) {
        store_step(pfA);
        __syncthreads();
        load_step(ks + 1, pfB);   // in flight under compute of ks
        compute_step();
        __syncthreads();
        store_step(pfB);
        __syncthreads();
        if (ks + 2 < 96) load_step(ks + 2, pfA);  // in flight under ks+1
        compute_step();
        __syncthreads();
    }

    // softmax per row r: row i_loc = wave*16 + quad*4 + r, cols nf*16+l16.
    const float g = 1.0f / (1.0f + __expf(-gate[0]));
    const float gs = (dir == 0) ? g : (1.0f - g);
    unsigned short* Pg = P + (((size_t)dir * 64 + bn) << 14);

    #pragma unroll
    for (int r = 0; r < 4; ++r) {
        const int i_loc = (wave << 4) + (quad << 2) + r;
        const float rq = rqv[i_loc];
        float v[8], m = -1e30f;
        #pragma unroll
        for (int nf = 0; nf < 8; ++nf) {
            v[nf] = acc[nf][r] * rq * rkv[(nf << 4) + l16];
            m = fmaxf(m, v[nf]);
        }
        #pragma unroll
        for (int off = 1; off < 16; off <<= 1) m = fmaxf(m, __shfl_xor(m, off));
        float s = 0.0f;
        #pragma unroll
        for (int nf = 0; nf < 8; ++nf) { v[nf] = __expf(v[nf] - m); s += v[nf]; }
        #pragma unroll
        for (int off = 1; off < 16; off <<= 1) s += __shfl_xor(s, off);
        const float inv = gs / s;
        const size_t rowo = (size_t)(i0 + i_loc) * 128;
        #pragma unroll
        for (int nf = 0; nf < 8; ++nf)
            Pg[rowo + (nf << 4) + l16] = f2bf(v[nf] * inv);
    }
}

// ---------------------------------------------------------------------------
// pv: per (ch, bn) plane, F = P1g@A1 + A2@P2g^T + g*rq1[h]*A2 + (1-g)*rq2[w]*A1.
// All inputs bf16 (P carries gate factors). Output fusion bf16.
// grid (24 ch, 64 bn), block 256.
// ---------------------------------------------------------------------------
__global__ __launch_bounds__(256)
void pv_mfma(const unsigned short* __restrict__ o1, const unsigned short* __restrict__ o2,
             const unsigned short* __restrict__ P, const float* __restrict__ norms,
             const float* __restrict__ gate, unsigned short* __restrict__ fusion)
{
    __shared__ unsigned short P1s[128][40];
    __shared__ unsigned short A2s[128][40];
    __shared__ unsigned short P2s[128][40];
    __shared__ unsigned short A1Ts[128][40];
    __shared__ float rqs[256];

    const int tid = threadIdx.x;
    const int ch  = blockIdx.x;
    const int bn  = blockIdx.y;
    const int b = bn >> 3, n = bn & 7;

    const size_t pbase = (size_t)b * C_DIM * N_PIX + ((size_t)n * C_PH + ch) * N_PIX;
    const unsigned short* A1 = o1 + pbase;
    const unsigned short* A2 = o2 + pbase;
    const unsigned short* P1 = P + ((size_t)bn << 14);
    const unsigned short* P2 = P + ((size_t)(64 + bn) << 14);
    unsigned short* Fp = fusion + pbase;

    const float g = 1.0f / (1.0f + __expf(-gate[0]));
    if (tid < 128)
        rqs[tid] = g * rsqrtf(fmaxf(norms[(((size_t)8 + b) * 8 + n) * 256 + tid], 1e-24f));
    else
        rqs[tid] = (1.0f - g) * rsqrtf(fmaxf(norms[(((size_t)b) * 8 + n) * 256 + 128 + (tid - 128)], 1e-24f));

    const int wave = tid >> 6, lane = tid & 63;
    const int quad = lane >> 4, l16 = lane & 15;
    const int i0w = wave << 5;
    const int koff = quad << 3;

    f32x4 acc[2][8];
    #pragma unroll
    for (int i = 0; i < 2; ++i)
        #pragma unroll
        for (int j = 0; j < 8; ++j) acc[i][j] = (f32x4){0.f, 0.f, 0.f, 0.f};

    for (int k0 = 0; k0 < 128; k0 += 32) {
        // natural tiles: P1 [i][j], A2 [h][w], P2 [w][j] — pure uint4 copies
        #pragma unroll
        for (int r = 0; r < 2; ++r) {
            const int u = tid + (r << 8);
            const int row = u >> 2, k8 = u & 3;
            const size_t go = (size_t)row * 128 + k0 + (k8 << 3);
            *(uint4*)(&P1s[row][k8 << 3]) = *(const uint4*)(P1 + go);
            *(uint4*)(&A2s[row][k8 << 3]) = *(const uint4*)(A2 + go);
            *(uint4*)(&P2s[row][k8 << 3]) = *(const uint4*)(P2 + go);
        }
        // A1^T tile: [w][h] from [h][w], 4x8 ushort transpose (threads 0..127)
        if (tid < 128) {
            const int wg = tid >> 3, hq = tid & 7;
            uint4 f[4];
            #pragma unroll
            for (int i = 0; i < 4; ++i)
                f[i] = *(const uint4*)(A1 + (size_t)(k0 + (hq << 2) + i) * 128 + (wg << 3));
            #pragma unroll
            for (int j = 0; j < 8; ++j) {
                uint2 pk;
                pk.x = pack2(((const unsigned short*)&f[0])[j], ((const unsigned short*)&f[1])[j]);
                pk.y = pack2(((const unsigned short*)&f[2])[j], ((const unsigned short*)&f[3])[j]);
                *(uint2*)(&A1Ts[(wg << 3) + j][hq << 2]) = pk;
            }
        }
        __syncthreads();

        bf16x8 p1f[2], a2f[2];
        #pragma unroll
        for (int mf = 0; mf < 2; ++mf) {
            p1f[mf] = *(const bf16x8*)(&P1s[i0w + (mf << 4) + l16][koff]);
            a2f[mf] = *(const bf16x8*)(&A2s[i0w + (mf << 4) + l16][koff]);
        }
        #pragma unroll
        for (int nf = 0; nf < 8; ++nf) {
            const bf16x8 b1 = *(const bf16x8*)(&A1Ts[(nf << 4) + l16][koff]);
            const bf16x8 b2 = *(const bf16x8*)(&P2s[(nf << 4) + l16][koff]);
            #pragma unroll
            for (int mf = 0; mf < 2; ++mf) {
                acc[mf][nf] = __builtin_amdgcn_mfma_f32_16x16x32_bf16(p1f[mf], b1, acc[mf][nf], 0, 0, 0);
                acc[mf][nf] = __builtin_amdgcn_mfma_f32_16x16x32_bf16(a2f[mf], b2, acc[mf][nf], 0, 0, 0);
            }
        }
        __syncthreads();
    }

    #pragma unroll
    for (int mf = 0; mf < 2; ++mf) {
        #pragma unroll
        for (int r = 0; r < 4; ++r) {
            const int i = i0w + (mf << 4) + (quad << 2) + r;
            const float c1 = rqs[i];
            #pragma unroll
            for (int nf = 0; nf < 8; ++nf) {
                const int w = (nf << 4) + l16;
                const size_t o = (size_t)i * 128 + w;
                const float F = acc[mf][nf][r] + c1 * bf2f(A2[o]) + rqs[128 + w] * bf2f(A1[o]);
                Fp[o] = f2bf(F);
            }
        }
    }
}

// ---------------------------------------------------------------------------
extern "C" void kernel_launch(void* const* d_in, const int* in_sizes, int n_in,
                              void* d_out, int out_size, void* d_ws, size_t ws_size,
                              hipStream_t stream)
{
    (void)in_sizes; (void)n_in; (void)out_size; (void)ws_size;
    const float* x1     = (const float*)d_in[0];
    const float* x2     = (const float*)d_in[1];
    const float* W_proj = (const float*)d_in[2];
    const float* b_proj = (const float*)d_in[3];
    const float* gate   = (const float*)d_in[4];
    // d_in[5], d_in[6]: pos_bias_h/w — per-head scalars, cancel in softmax.
    const float* W_m1   = (const float*)d_in[7];
    const float* b_m1   = (const float*)d_in[8];
    const float* W_m2   = (const float*)d_in[9];
    const float* b_m2   = (const float*)d_in[10];

    unsigned short* o1    = (unsigned short*)d_ws;       // out1 bf16 -> t1
    unsigned short* o2    = o1 + ELEMS;                  // out2 bf16 -> t2
    float*          norms = (float*)(o2 + ELEMS);        // 32768 f32

    unsigned short* fusion = (unsigned short*)d_out;     // bf16, dead by conv7
    unsigned short* Pbuf   = fusion + ELEMS;             // 2*64*16384 bf16

    const dim3 cgrid(64, 3, 8);
    conv_f32in<<<cgrid, 256, 0, stream>>>(x1, W_proj, b_proj, o1);
    conv_f32in<<<cgrid, 256, 0, stream>>>(x2, W_proj, b_proj, o2);

    hipMemsetAsync(norms, 0, 32768 * sizeof(float), stream);
    norms_kernel<<<dim3(8, 8, 8), 256, 0, stream>>>(o1, o2, norms);

    scores_softmax<<<dim3(2, 64, 2), 256, 0, stream>>>(o1, o2, norms, gate, Pbuf);
    pv_mfma<<<dim3(24, 64), 256, 0, stream>>>(o1, o2, Pbuf, norms, gate, fusion);

    conv_b16in<0><<<cgrid, 256, 0, stream>>>(fusion, W_proj, b_proj, o1, nullptr, nullptr);
    conv_b16in<1><<<cgrid, 256, 0, stream>>>(o1, W_m1, b_m1, o2, nullptr, nullptr);
    conv_b16in<2><<<cgrid, 256, 0, stream>>>(o2, W_m2, b_m2, d_out, x1, x2);
}

// Round 2
// 635.342 us; speedup vs baseline: 1.0336x; 1.0336x over previous
//
#include <hip/hip_runtime.h>
#include <math.h>

// BCAM: x1,x2 [8,192,128,128] f32. heads=8, c=24, temperature=0.01.
// R4: all-bf16 MFMA pipeline (conv1/2, norms, scores+softmax, pv, conv5/6/7).
// R6: scores_softmax rewritten register-direct:
//   - transpose_norms kernel: writes plane-transposed o1T/o2T (bf16) AND
//     fuses the token sum-of-squares reduction (norms_kernel deleted).
//   - scores: no LDS staging, no k-loop barriers. B/A fragments are loaded
//     straight from global as uint4 (tokens row-major, k contiguous; dir=1
//     reads the transposed planes). 1024-thr blocks = 16 waves = 4 i-waves
//     x 4 K-split waves -> 50% occupancy vs 12.5% before; partial S combined
//     via LDS in the epilogue only.
//   - pv reads A1T directly from o1T (in-kernel shuffle transpose deleted).
// Memory: ws = o1 + o2 + norms + Pbuf (~105 MB). d_out = [o2T->fusion][o1T]
//   (o2T dead before pv writes fusion over it; o1T dead before conv7).
// Numerics: bf16 rounding in logits ~0.005 RMS, far below 0.152 threshold.
// pos_bias dropped (per-head scalar, softmax shift-invariant).
// V = UNNORMALIZED tokens (v1=k1 binds before l2norm).

#define N_PIX 16384
#define W_DIM 128
#define C_DIM 192
#define C_PH  24
#define ELEMS 25165824  // 8*192*128*128
#define TINV  100.0f

typedef __bf16 bf16x8 __attribute__((ext_vector_type(8)));
typedef float  f32x4  __attribute__((ext_vector_type(4)));

__device__ __forceinline__ unsigned short f2bf(float f) {
    union { float f; unsigned u; } x; x.f = f;
    unsigned r = x.u + 0x7FFF + ((x.u >> 16) & 1);
    return (unsigned short)(r >> 16);
}
__device__ __forceinline__ float bf2f(unsigned short h) {
    union { unsigned u; float f; } x; x.u = ((unsigned)h) << 16; return x.f;
}
__device__ __forceinline__ unsigned pack2(unsigned short a, unsigned short b) {
    return (unsigned)a | ((unsigned)b << 16);
}

// ---------------------------------------------------------------------------
// conv1x1, f32 input -> bf16 output (conv1/conv2).
// grid (64 p-tiles, 3 m-tiles, 8 b), block 256. Tile 64m x 256p.
// ---------------------------------------------------------------------------
__global__ __launch_bounds__(256)
void conv_f32in(const float* __restrict__ X, const float* __restrict__ Wt,
                const float* __restrict__ bias, unsigned short* __restrict__ Y)
{
    __shared__ unsigned short Ah[64][40];
    __shared__ unsigned short Bh[256][40];

    const int tid = threadIdx.x;
    const int p0 = blockIdx.x << 8;
    const int m0 = blockIdx.y << 6;
    const int b  = blockIdx.z;
    const float* Xb = X + (size_t)b * C_DIM * N_PIX;

    const int wave = tid >> 6, lane = tid & 63;
    const int quad = lane >> 4, l16 = lane & 15;
    const int mw = (wave & 1) << 5;
    const int nw = (wave >> 1) << 7;
    const int koff = quad << 3;

    f32x4 acc[2][8];
    #pragma unroll
    for (int i = 0; i < 2; ++i)
        #pragma unroll
        for (int j = 0; j < 8; ++j) acc[i][j] = (f32x4){0.f, 0.f, 0.f, 0.f};

    for (int k0 = 0; k0 < C_DIM; k0 += 32) {
        // A (weights) 64m x 32k
        #pragma unroll
        for (int i = 0; i < 2; ++i) {
            const int a = (tid << 1) + i;
            const int m = a >> 3, kq = a & 7;
            const float4 v = *(const float4*)(Wt + (size_t)(m0 + m) * C_DIM + k0 + (kq << 2));
            uint2 pk; pk.x = pack2(f2bf(v.x), f2bf(v.y)); pk.y = pack2(f2bf(v.z), f2bf(v.w));
            *(uint2*)(&Ah[m][kq << 2]) = pk;
        }
        // B (pixels) 32k x 256p, 4x4 transpose. kq in low bits -> spread banks.
        #pragma unroll
        for (int r = 0; r < 2; ++r) {
            const int u = tid + (r << 8);
            const int kq = u & 7, p4 = (u >> 3) << 2;
            float4 f[4];
            #pragma unroll
            for (int i = 0; i < 4; ++i)
                f[i] = *(const float4*)(Xb + (size_t)(k0 + (kq << 2) + i) * N_PIX + p0 + p4);
            #pragma unroll
            for (int j = 0; j < 4; ++j) {
                uint2 pk;
                pk.x = pack2(f2bf((&f[0].x)[j]), f2bf((&f[1].x)[j]));
                pk.y = pack2(f2bf((&f[2].x)[j]), f2bf((&f[3].x)[j]));
                *(uint2*)(&Bh[p4 + j][kq << 2]) = pk;
            }
        }
        __syncthreads();

        bf16x8 af[2];
        #pragma unroll
        for (int mf = 0; mf < 2; ++mf)
            af[mf] = *(const bf16x8*)(&Ah[mw + (mf << 4) + l16][koff]);
        #pragma unroll
        for (int nf = 0; nf < 8; ++nf) {
            const bf16x8 bfr = *(const bf16x8*)(&Bh[nw + (nf << 4) + l16][koff]);
            #pragma unroll
            for (int mf = 0; mf < 2; ++mf)
                acc[mf][nf] = __builtin_amdgcn_mfma_f32_16x16x32_bf16(af[mf], bfr, acc[mf][nf], 0, 0, 0);
        }
        __syncthreads();
    }

    const size_t outb = (size_t)b * C_DIM * N_PIX;
    #pragma unroll
    for (int mf = 0; mf < 2; ++mf) {
        #pragma unroll
        for (int r = 0; r < 4; ++r) {
            const int m = m0 + mw + (mf << 4) + (quad << 2) + r;
            const float bm = bias[m];
            const size_t row = outb + (size_t)m * N_PIX;
            #pragma unroll
            for (int nf = 0; nf < 8; ++nf) {
                const int p = p0 + nw + (nf << 4) + l16;
                Y[row + p] = f2bf(acc[mf][nf][r] + bm);
            }
        }
    }
}

// ---------------------------------------------------------------------------
// conv1x1, bf16 input (conv5/6/7). MODE 0: bf16 out; 1: GELU, bf16 out;
// 2: + R1 + R2 (f32), f32 out.
// ---------------------------------------------------------------------------
template<int MODE>
__global__ __launch_bounds__(256)
void conv_b16in(const unsigned short* __restrict__ X, const float* __restrict__ Wt,
                const float* __restrict__ bias, void* __restrict__ Yv,
                const float* __restrict__ R1, const float* __restrict__ R2)
{
    __shared__ unsigned short Ah[64][40];
    __shared__ unsigned short Bh[256][40];

    const int tid = threadIdx.x;
    const int p0 = blockIdx.x << 8;
    const int m0 = blockIdx.y << 6;
    const int b  = blockIdx.z;
    const unsigned short* Xb = X + (size_t)b * C_DIM * N_PIX;

    const int wave = tid >> 6, lane = tid & 63;
    const int quad = lane >> 4, l16 = lane & 15;
    const int mw = (wave & 1) << 5;
    const int nw = (wave >> 1) << 7;
    const int koff = quad << 3;

    f32x4 acc[2][8];
    #pragma unroll
    for (int i = 0; i < 2; ++i)
        #pragma unroll
        for (int j = 0; j < 8; ++j) acc[i][j] = (f32x4){0.f, 0.f, 0.f, 0.f};

    for (int k0 = 0; k0 < C_DIM; k0 += 32) {
        #pragma unroll
        for (int i = 0; i < 2; ++i) {
            const int a = (tid << 1) + i;
            const int m = a >> 3, kq = a & 7;
            const float4 v = *(const float4*)(Wt + (size_t)(m0 + m) * C_DIM + k0 + (kq << 2));
            uint2 pk; pk.x = pack2(f2bf(v.x), f2bf(v.y)); pk.y = pack2(f2bf(v.z), f2bf(v.w));
            *(uint2*)(&Ah[m][kq << 2]) = pk;
        }
        // B: 32k x 256p. Thread: 4 k-rows (kq) x 8 p. Pure ushort transpose.
        {
            const int kq = tid & 7, pg = (tid >> 3) << 3;
            uint4 f[4];
            #pragma unroll
            for (int i = 0; i < 4; ++i)
                f[i] = *(const uint4*)(Xb + (size_t)(k0 + (kq << 2) + i) * N_PIX + p0 + pg);
            #pragma unroll
            for (int j = 0; j < 8; ++j) {
                const unsigned short e0 = ((const unsigned short*)&f[0])[j];
                const unsigned short e1 = ((const unsigned short*)&f[1])[j];
                const unsigned short e2 = ((const unsigned short*)&f[2])[j];
                const unsigned short e3 = ((const unsigned short*)&f[3])[j];
                uint2 pk; pk.x = pack2(e0, e1); pk.y = pack2(e2, e3);
                *(uint2*)(&Bh[pg + j][kq << 2]) = pk;
            }
        }
        __syncthreads();

        bf16x8 af[2];
        #pragma unroll
        for (int mf = 0; mf < 2; ++mf)
            af[mf] = *(const bf16x8*)(&Ah[mw + (mf << 4) + l16][koff]);
        #pragma unroll
        for (int nf = 0; nf < 8; ++nf) {
            const bf16x8 bfr = *(const bf16x8*)(&Bh[nw + (nf << 4) + l16][koff]);
            #pragma unroll
            for (int mf = 0; mf < 2; ++mf)
                acc[mf][nf] = __builtin_amdgcn_mfma_f32_16x16x32_bf16(af[mf], bfr, acc[mf][nf], 0, 0, 0);
        }
        __syncthreads();
    }

    const size_t outb = (size_t)b * C_DIM * N_PIX;
    #pragma unroll
    for (int mf = 0; mf < 2; ++mf) {
        #pragma unroll
        for (int r = 0; r < 4; ++r) {
            const int m = m0 + mw + (mf << 4) + (quad << 2) + r;
            const float bm = bias[m];
            const size_t row = outb + (size_t)m * N_PIX;
            #pragma unroll
            for (int nf = 0; nf < 8; ++nf) {
                const int p = p0 + nw + (nf << 4) + l16;
                float v = acc[mf][nf][r] + bm;
                if (MODE == 1) v = 0.5f * v * (1.0f + erff(v * 0.70710678118654752f));
                if (MODE == 2) {
                    v += R1[row + p] + R2[row + p];
                    ((float*)Yv)[row + p] = v;
                } else {
                    ((unsigned short*)Yv)[row + p] = f2bf(v);
                }
            }
        }
    }
}

// ---------------------------------------------------------------------------
// transpose_norms: per (ch,b,src) 128x128 plane, write plane-transposed copy
// AND accumulate token sum-of-squares. Thread = one 8x8 tile, in-register
// transpose (no LDS for data). norms[src][b][n][dir*128+t] via atomics.
// grid (192 ch, 8 b, 2 src), block 256.
// ---------------------------------------------------------------------------
__global__ __launch_bounds__(256)
void transpose_norms(const unsigned short* __restrict__ o1,
                     const unsigned short* __restrict__ o2,
                     unsigned short* __restrict__ o1T,
                     unsigned short* __restrict__ o2T,
                     float* __restrict__ norms)
{
    __shared__ float hs[128];
    __shared__ float wss[128];

    const int tid = threadIdx.x;
    const int ch  = blockIdx.x;
    const int b   = blockIdx.y;
    const int src = blockIdx.z;
    const int n   = ch / 24;

    const size_t poff = ((size_t)b * C_DIM + ch) * N_PIX;
    const unsigned short* pin = (src ? o2 : o1) + poff;
    unsigned short* pout      = (src ? o2T : o1T) + poff;

    if (tid >= 128) wss[tid - 128] = 0.0f;
    __syncthreads();

    const int h0 = (tid >> 4) << 3;   // 8-row group (exclusive per 16-thread group)
    const int w0 = (tid & 15) << 3;   // 8-col group

    uint4 r[8];
    #pragma unroll
    for (int i = 0; i < 8; ++i)
        r[i] = *(const uint4*)(pin + (size_t)(h0 + i) * W_DIM + w0);

    // transposed store: oT[w0+j][h0..h0+7]
    #pragma unroll
    for (int j = 0; j < 8; ++j) {
        uint4 o;
        unsigned short* op = (unsigned short*)&o;
        #pragma unroll
        for (int i = 0; i < 8; ++i)
            op[i] = ((const unsigned short*)&r[i])[j];
        *(uint4*)(pout + (size_t)(w0 + j) * W_DIM + h0) = o;
    }

    // partial sums of squares
    float hp[8], wp[8];
    #pragma unroll
    for (int i = 0; i < 8; ++i) { hp[i] = 0.0f; wp[i] = 0.0f; }
    #pragma unroll
    for (int i = 0; i < 8; ++i) {
        #pragma unroll
        for (int j = 0; j < 8; ++j) {
            const float v = bf2f(((const unsigned short*)&r[i])[j]);
            hp[i] += v * v;
            wp[j] += v * v;
        }
    }
    // h-rows: the 16 lanes sharing h0 are lanes differing in bits 0..3.
    #pragma unroll
    for (int i = 0; i < 8; ++i) {
        #pragma unroll
        for (int off = 1; off < 16; off <<= 1) hp[i] += __shfl_xor(hp[i], off);
    }
    const int l16 = tid & 15;
    if (l16 < 8) hs[h0 + l16] = hp[l16];  // each group owns its 8 h rows
    // w-cols: lanes sharing w0 within a wave differ in bits 4,5.
    #pragma unroll
    for (int j = 0; j < 8; ++j) {
        wp[j] += __shfl_xor(wp[j], 16);
        wp[j] += __shfl_xor(wp[j], 32);
    }
    if ((tid & 63) < 16) {
        #pragma unroll
        for (int j = 0; j < 8; ++j) atomicAdd(&wss[w0 + j], wp[j]);
    }
    __syncthreads();

    float* np_ = norms + ((size_t)(src * 8 + b) * 8 + n) * 256;
    if (tid < 128) atomicAdd(&np_[tid], hs[tid]);
    else           atomicAdd(&np_[tid], wss[tid - 128]);
}

// ---------------------------------------------------------------------------
// Fused scores+softmax: S = Qbf.Kbf^T (full K=3072), scale 100*rq*rk, row
// softmax, pre-scale by gate weight, write P bf16.
// R6: register-direct fragments, no LDS staging, no k-loop barriers.
// grid (2 i-tiles, 64 bn, 2 dir), block 1024 = 16 waves (4 i-waves x 4 K-split
// waves). Each wave: 16 i-rows x 128 j, K-range 768 (24 steps). Partial S
// combined through LDS in the epilogue; kw==0 waves do softmax + store.
// ---------------------------------------------------------------------------
__global__ __launch_bounds__(1024)
void scores_softmax(const unsigned short* __restrict__ o1,
                    const unsigned short* __restrict__ o2,
                    const unsigned short* __restrict__ o1T,
                    const unsigned short* __restrict__ o2T,
                    const float* __restrict__ norms, const float* __restrict__ gate,
                    unsigned short* __restrict__ P)
{
    __shared__ float Sred[3][4][16][132];
    __shared__ float rqv[64], rkv[128];

    const int tid = threadIdx.x;
    const int i0  = blockIdx.x << 6;
    const int bn  = blockIdx.y;
    const int dir = blockIdx.z;
    const int b = bn >> 3, n = bn & 7;

    const size_t base = (size_t)b * C_DIM * N_PIX + (size_t)n * C_PH * N_PIX;
    // dir0: tokens = h-rows (natural planes). dir1: tokens = w-rows (transposed planes).
    const unsigned short* Qb = (dir == 0 ? o2 : o1T) + base;
    const unsigned short* Kb = (dir == 0 ? o1 : o2T) + base;

    const int qsrc = (dir == 0) ? 1 : 0;
    const float* qn_g = norms + ((size_t)(qsrc * 8 + b) * 8 + n) * 256 + dir * 128;
    const float* kn_g = norms + ((size_t)((1 - qsrc) * 8 + b) * 8 + n) * 256 + dir * 128;

    if (tid < 64)        rqv[tid]      = TINV * rsqrtf(fmaxf(qn_g[i0 + tid], 1e-24f));
    else if (tid < 192)  rkv[tid - 64] = rsqrtf(fmaxf(kn_g[tid - 64], 1e-24f));

    const int wave = tid >> 6, lane = tid & 63;
    const int iw = wave & 3;    // i-wave: rows i0 + iw*16 .. +15
    const int kw = wave >> 2;   // K-split group: k = kw*768 .. +768
    const int quad = lane >> 4, l16 = lane & 15;

    // per-lane row bases (token-row major, k contiguous within plane row)
    const unsigned short* rq = Qb + (size_t)(i0 + (iw << 4) + l16) * W_DIM + (quad << 3);
    const unsigned short* rk = Kb + (size_t)l16 * W_DIM + (quad << 3);

    f32x4 acc[8];
    #pragma unroll
    for (int j = 0; j < 8; ++j) acc[j] = (f32x4){0.f, 0.f, 0.f, 0.f};

    #pragma unroll 2
    for (int s = 0; s < 24; ++s) {
        const int ks = kw * 24 + s;                 // global k-step 0..95
        const size_t off = (size_t)(ks >> 2) * N_PIX + (size_t)((ks & 3) << 5);
        const uint4 qf = *(const uint4*)(rq + off);
        uint4 kf[8];
        #pragma unroll
        for (int nf = 0; nf < 8; ++nf)
            kf[nf] = *(const uint4*)(rk + off + (nf << 11));   // +nf*16 rows
        const bf16x8 a = *(const bf16x8*)&qf;
        #pragma unroll
        for (int nf = 0; nf < 8; ++nf)
            acc[nf] = __builtin_amdgcn_mfma_f32_16x16x32_bf16(a, *(const bf16x8*)&kf[nf], acc[nf], 0, 0, 0);
    }

    if (kw != 0) {
        float* dst = &Sred[kw - 1][iw][0][0];
        #pragma unroll
        for (int nf = 0; nf < 8; ++nf)
            #pragma unroll
            for (int r = 0; r < 4; ++r)
                dst[(size_t)((quad << 2) + r) * 132 + (nf << 4) + l16] = acc[nf][r];
    }
    __syncthreads();
    if (kw != 0) return;

    // kw==0 waves: combine partials, softmax, store P.
    const float g = 1.0f / (1.0f + __expf(-gate[0]));
    const float gs = (dir == 0) ? g : (1.0f - g);
    unsigned short* Pg = P + (((size_t)dir * 64 + bn) << 14);

    #pragma unroll
    for (int r = 0; r < 4; ++r) {
        const int row16 = (quad << 2) + r;
        const int i_loc = (iw << 4) + row16;
        const float rqs = rqv[i_loc];
        float v[8], m = -1e30f;
        #pragma unroll
        for (int nf = 0; nf < 8; ++nf) {
            const int col = (nf << 4) + l16;
            float sv = acc[nf][r]
                     + Sred[0][iw][row16][col]
                     + Sred[1][iw][row16][col]
                     + Sred[2][iw][row16][col];
            v[nf] = sv * rqs * rkv[col];
            m = fmaxf(m, v[nf]);
        }
        #pragma unroll
        for (int off = 1; off < 16; off <<= 1) m = fmaxf(m, __shfl_xor(m, off));
        float s = 0.0f;
        #pragma unroll
        for (int nf = 0; nf < 8; ++nf) { v[nf] = __expf(v[nf] - m); s += v[nf]; }
        #pragma unroll
        for (int off = 1; off < 16; off <<= 1) s += __shfl_xor(s, off);
        const float inv = gs / s;
        const size_t rowo = (size_t)(i0 + i_loc) * 128;
        #pragma unroll
        for (int nf = 0; nf < 8; ++nf)
            Pg[rowo + (nf << 4) + l16] = f2bf(v[nf] * inv);
    }
}

// ---------------------------------------------------------------------------
// pv: per (ch, bn) plane, F = P1g@A1 + A2@P2g^T + g*rq1[h]*A2 + (1-g)*rq2[w]*A1.
// All inputs bf16 (P carries gate factors). A1^T tile read directly from o1T.
// grid (24 ch, 64 bn), block 256.
// ---------------------------------------------------------------------------
__global__ __launch_bounds__(256)
void pv_mfma(const unsigned short* __restrict__ o1, const unsigned short* __restrict__ o2,
             const unsigned short* __restrict__ o1T,
             const unsigned short* __restrict__ P, const float* __restrict__ norms,
             const float* __restrict__ gate, unsigned short* __restrict__ fusion)
{
    __shared__ unsigned short P1s[128][40];
    __shared__ unsigned short A2s[128][40];
    __shared__ unsigned short P2s[128][40];
    __shared__ unsigned short A1Ts[128][40];
    __shared__ float rqs[256];

    const int tid = threadIdx.x;
    const int ch  = blockIdx.x;
    const int bn  = blockIdx.y;
    const int b = bn >> 3, n = bn & 7;

    const size_t pbase = (size_t)b * C_DIM * N_PIX + ((size_t)n * C_PH + ch) * N_PIX;
    const unsigned short* A1  = o1 + pbase;
    const unsigned short* A2  = o2 + pbase;
    const unsigned short* A1T = o1T + pbase;
    const unsigned short* P1 = P + ((size_t)bn << 14);
    const unsigned short* P2 = P + ((size_t)(64 + bn) << 14);
    unsigned short* Fp = fusion + pbase;

    const float g = 1.0f / (1.0f + __expf(-gate[0]));
    if (tid < 128)
        rqs[tid] = g * rsqrtf(fmaxf(norms[(((size_t)8 + b) * 8 + n) * 256 + tid], 1e-24f));
    else
        rqs[tid] = (1.0f - g) * rsqrtf(fmaxf(norms[(((size_t)b) * 8 + n) * 256 + 128 + (tid - 128)], 1e-24f));

    const int wave = tid >> 6, lane = tid & 63;
    const int quad = lane >> 4, l16 = lane & 15;
    const int i0w = wave << 5;
    const int koff = quad << 3;

    f32x4 acc[2][8];
    #pragma unroll
    for (int i = 0; i < 2; ++i)
        #pragma unroll
        for (int j = 0; j < 8; ++j) acc[i][j] = (f32x4){0.f, 0.f, 0.f, 0.f};

    for (int k0 = 0; k0 < 128; k0 += 32) {
        // all four tiles are natural row-major uint4 copies now
        #pragma unroll
        for (int r = 0; r < 2; ++r) {
            const int u = tid + (r << 8);
            const int row = u >> 2, k8 = u & 3;
            const size_t go = (size_t)row * 128 + k0 + (k8 << 3);
            *(uint4*)(&P1s[row][k8 << 3])  = *(const uint4*)(P1 + go);
            *(uint4*)(&A2s[row][k8 << 3])  = *(const uint4*)(A2 + go);
            *(uint4*)(&P2s[row][k8 << 3])  = *(const uint4*)(P2 + go);
            *(uint4*)(&A1Ts[row][k8 << 3]) = *(const uint4*)(A1T + go);
        }
        __syncthreads();

        bf16x8 p1f[2], a2f[2];
        #pragma unroll
        for (int mf = 0; mf < 2; ++mf) {
            p1f[mf] = *(const bf16x8*)(&P1s[i0w + (mf << 4) + l16][koff]);
            a2f[mf] = *(const bf16x8*)(&A2s[i0w + (mf << 4) + l16][koff]);
        }
        #pragma unroll
        for (int nf = 0; nf < 8; ++nf) {
            const bf16x8 b1 = *(const bf16x8*)(&A1Ts[(nf << 4) + l16][koff]);
            const bf16x8 b2 = *(const bf16x8*)(&P2s[(nf << 4) + l16][koff]);
            #pragma unroll
            for (int mf = 0; mf < 2; ++mf) {
                acc[mf][nf] = __builtin_amdgcn_mfma_f32_16x16x32_bf16(p1f[mf], b1, acc[mf][nf], 0, 0, 0);
                acc[mf][nf] = __builtin_amdgcn_mfma_f32_16x16x32_bf16(a2f[mf], b2, acc[mf][nf], 0, 0, 0);
            }
        }
        __syncthreads();
    }

    #pragma unroll
    for (int mf = 0; mf < 2; ++mf) {
        #pragma unroll
        for (int r = 0; r < 4; ++r) {
            const int i = i0w + (mf << 4) + (quad << 2) + r;
            const float c1 = rqs[i];
            #pragma unroll
            for (int nf = 0; nf < 8; ++nf) {
                const int w = (nf << 4) + l16;
                const size_t o = (size_t)i * 128 + w;
                const float F = acc[mf][nf][r] + c1 * bf2f(A2[o]) + rqs[128 + w] * bf2f(A1[o]);
                Fp[o] = f2bf(F);
            }
        }
    }
}

// ---------------------------------------------------------------------------
extern "C" void kernel_launch(void* const* d_in, const int* in_sizes, int n_in,
                              void* d_out, int out_size, void* d_ws, size_t ws_size,
                              hipStream_t stream)
{
    (void)in_sizes; (void)n_in; (void)out_size; (void)ws_size;
    const float* x1     = (const float*)d_in[0];
    const float* x2     = (const float*)d_in[1];
    const float* W_proj = (const float*)d_in[2];
    const float* b_proj = (const float*)d_in[3];
    const float* gate   = (const float*)d_in[4];
    // d_in[5], d_in[6]: pos_bias_h/w — per-head scalars, cancel in softmax.
    const float* W_m1   = (const float*)d_in[7];
    const float* b_m1   = (const float*)d_in[8];
    const float* W_m2   = (const float*)d_in[9];
    const float* b_m2   = (const float*)d_in[10];

    unsigned short* o1    = (unsigned short*)d_ws;       // out1 bf16
    unsigned short* o2    = o1 + ELEMS;                  // out2 bf16
    float*          norms = (float*)(o2 + ELEMS);        // 32768 f32
    unsigned short* Pbuf  = (unsigned short*)(norms + 32768);  // 2*64*16384 bf16

    // d_out aliasing: [o2T (dead before pv) -> fusion][o1T (dead before conv7)]
    unsigned short* o2T    = (unsigned short*)d_out;
    unsigned short* fusion = o2T;
    unsigned short* o1T    = o2T + ELEMS;

    const dim3 cgrid(64, 3, 8);
    conv_f32in<<<cgrid, 256, 0, stream>>>(x1, W_proj, b_proj, o1);
    conv_f32in<<<cgrid, 256, 0, stream>>>(x2, W_proj, b_proj, o2);

    hipMemsetAsync(norms, 0, 32768 * sizeof(float), stream);
    transpose_norms<<<dim3(192, 8, 2), 256, 0, stream>>>(o1, o2, o1T, o2T, norms);

    scores_softmax<<<dim3(2, 64, 2), 1024, 0, stream>>>(o1, o2, o1T, o2T, norms, gate, Pbuf);
    pv_mfma<<<dim3(24, 64), 256, 0, stream>>>(o1, o2, o1T, Pbuf, norms, gate, fusion);

    conv_b16in<0><<<cgrid, 256, 0, stream>>>(fusion, W_proj, b_proj, o1, nullptr, nullptr);
    conv_b16in<1><<<cgrid, 256, 0, stream>>>(o1, W_m1, b_m1, o2, nullptr, nullptr);
    conv_b16in<2><<<cgrid, 256, 0, stream>>>(o2, W_m2, b_m2, d_out, x1, x2);
}